// Round 11
// baseline (379.182 us; speedup 1.0000x reference)
//
#include <hip/hip_runtime.h>
#include <hip/hip_bf16.h>
#include <stdint.h>

#define BATCH 128
#define SEQ   512
#define NW    6
#define DIM   64
#define NELEM (BATCH * SEQ * NW)   // 393216
#define PI_F  3.14159265358979323846f

typedef float v2f __attribute__((ext_vector_type(2)));
typedef uint16_t u16x8 __attribute__((ext_vector_type(8)));

__device__ __forceinline__ v2f pkfma(float s, v2f m, v2f a) {
    return __builtin_elementwise_fma((v2f){s, s}, m, a);
}

// Single-instruction DPP add stage (bound_ctrl=true folds to v_add_f32_dpp).
template <int CTRL>
__device__ __forceinline__ float dpp_add(float v) {
    return v + __int_as_float(__builtin_amdgcn_update_dpp(
        0, __float_as_int(v), CTRL, 0xF, 0xF, true));
}

// 6-way interleaved reduction stage (r8-verified: shr1,2,4,8 + bcast15,31
// -> totals land in lane 63).
template <int CTRL>
__device__ __forceinline__ void red6(float v[6]) {
#pragma unroll
    for (int k = 0; k < 6; ++k) v[k] = dpp_add<CTRL>(v[k]);
}

// DPP move, bound_ctrl=true (all CTRLs used valid on every lane).
template <int CTRL>
__device__ __forceinline__ float dpp_mov(float x) {
    return __int_as_float(__builtin_amdgcn_update_dpp(
        0, __float_as_int(x), CTRL, 0xF, 0xF, true));
}

__device__ __forceinline__ float ldf(const void* p, int i, bool bf) {
    if (bf) {
        uint32_t u = (uint32_t)((const uint16_t*)p)[i];
        return __uint_as_float(u << 16);
    }
    return ((const float*)p)[i];
}

// ---------------------------------------------------------------------------
// Kernel 1 (msetup + misc):
//  - blocks [0,32): 4 waves/block evolve one (dir,col) basis column; writes
//    Mgc split by COMPONENT in the packed-pair layout k_sim's matvec wants:
//    Mgc[((dir*2+comp)*64 + row)*64 + (p2*8+jl)*2 + (jh&1)],
//    where col = 8*jh+jl, p2 = jh>>1.
//  - block 32: misc fills + flag post
// ---------------------------------------------------------------------------
__global__ void k_prep(const void* ang, const void* poly, const void* fp,
                       const void* bp, const void* fc, const void* bc,
                       float* __restrict__ misc, float* __restrict__ Mgc,
                       int* __restrict__ flag) {
    __shared__ int cnt;
    if (threadIdx.x == 0) cnt = 0;
    __syncthreads();
    {
        uint32_t w = ((const uint32_t*)ang)[threadIdx.x & 255];
        uint32_t e = (w >> 8) & 0xFFu;
        if (e >= 0x3Au && e <= 0x41u) atomicAdd(&cnt, 1);
    }
    __syncthreads();
    const bool bf = (cnt >= 128);

    if (blockIdx.x == 32) {
        if (threadIdx.x == 0)      misc[76] = ldf(fc, 0, bf);
        else if (threadIdx.x == 1) misc[77] = ldf(bc, 0, bf);
        else if (threadIdx.x == 2) *flag = bf ? 1 : 0;
        return;
    }

    const int lane = threadIdx.x & 63;
    const int tix  = blockIdx.x * 4 + (threadIdx.x >> 6);
    const int dir  = tix >> 6;
    const int col  = tix & 63;
    const void* prm = dir ? bp : fp;
    const int p = lane;

    float yr = (p == col) ? 1.f : 0.f;
    float yi = 0.f;

#pragma unroll
    for (int d = 0; d < 4; ++d) {
        const float th = 0.5f * PI_F * ldf(poly, d, bf) *
                         (float)(6 - 2 * (int)__popc((unsigned)p));
        float s, c;
        __sincosf(th, &s, &c);
        const float nr = yr * c + yi * s;
        const float ni = yi * c - yr * s;
        yr = nr; yi = ni;
#pragma unroll
        for (int k = 0; k < 6; ++k) {
            const int cw = k, tw = (k + 1) % 6;
            const int src = p ^ (((p >> (5 - cw)) & 1) << (5 - tw));
            yr = __shfl(yr, src, 64);
            yi = __shfl(yi, src, 64);
        }
    }

    int idx = 0;
#pragma unroll
    for (int l = 0; l < 2; ++l) {
#pragma unroll
        for (int w = 0; w < 6; ++w) {
            float cx, sx, cy, sy, cz, sz;
            __sincosf(0.5f * ldf(prm, idx + 0, bf), &sx, &cx);
            __sincosf(0.5f * ldf(prm, idx + 1, bf), &sy, &cy);
            __sincosf(0.5f * ldf(prm, idx + 2, bf), &sz, &cz);
            idx += 3;
            const float A = cy * cx, B = sy * sx, C = sy * cx, D = cy * sx;
            const float U00r = cz * A + sz * B, U00i = cz * B - sz * A;
            const float U11r = U00r,            U11i = sz * A - cz * B;
            const float Xr   = cz * C + sz * D, Xi   = sz * C - cz * D;
            const int m  = 1 << (5 - w);
            const int bb = (p >> (5 - w)) & 1;
            const float C1r = bb ? U11r : U00r;
            const float C1i = bb ? U11i : U00i;
            const float C2r = bb ? Xr : -Xr;
            const float C2i = Xi;
            const float pr = __shfl_xor(yr, m, 64);
            const float pi = __shfl_xor(yi, m, 64);
            const float nr = C1r * yr - C1i * yi + C2r * pr - C2i * pi;
            const float ni = C1r * yi + C1i * yr + C2r * pi + C2i * pr;
            yr = nr; yi = ni;
        }
#pragma unroll
        for (int k = 0; k < 5; ++k) {
            const int src = p ^ (((p >> (5 - k)) & 1) << (5 - (k + 1)));
            yr = __shfl(yr, src, 64);
            yi = __shfl(yi, src, 64);
        }
    }

    // component-split, packed-pair layout (see header comment)
    const int jh = col >> 3, jl = col & 7;
    const int off = ((jh >> 1) * 8 + jl) * 2 + (jh & 1);
    Mgc[((size_t)(dir * 2 + 0) * 64 + p) * 64 + off] = yr;
    Mgc[((size_t)(dir * 2 + 1) * 64 + p) * 64 + off] = yi;
}

// ---------------------------------------------------------------------------
// Kernel 2: recurrent sim — TWO waves/chain split by COMPLEX COMPONENT:
//   * e(h) is real, so yr = Mr·e and yi = Mi·e are independent REAL matvecs;
//     wave 0 owns Mr (full row, 64 VGPRs — under the proven 132 ceiling),
//     wave 1 owns Mi. Packed-pair matvec: 32 pkfma + 8 fma (vs 72).
//   * the measurement separates by component: Z_w = Σ±(yr²+yi²) and
//     X_w = Σ(yr·yr^m + yi·yi^m), and cx/sx fold linearly — each wave
//     computes its component's 6 v-totals with r8's verified dots + tree.
//   * the ONLY exchange is 6 scalars/wave: lane-63 writes 2×b128, one
//     barrier, broadcast read + 6 adds. No per-lane partial exchange.
//   Per-wave issue ~halves vs r8/r10 (same fixed barrier+LDS round-trip).
// ---------------------------------------------------------------------------
__global__ void __launch_bounds__(128, 1) k_sim(const void* __restrict__ ang,
                                                const float* __restrict__ Mgc,
                                                float* __restrict__ hbuf,
                                                const int* __restrict__ flag) {
    const int tid   = threadIdx.x;
    const int lane  = tid & 63;
    const int wv    = tid >> 6;              // wave 0: real, wave 1: imag
    const int chain = blockIdx.x;            // 0..255
    const int dir   = chain >> 7;
    const int b     = chain & 127;
    const bool bf   = (*flag != 0);

    __shared__ __align__(16) float  cl[SEQ * 12];   // 24 KB cos/sin(x)
    __shared__ __align__(16) float  zb[SEQ * NW];   // 12 KB output buffer
    __shared__ __align__(16) float  tot[2][2][8];   // ping-pong totals, 128 B

    // ---- stage: convert this chain's 3072 angles -> cos/sin in LDS ----
    if (!bf) {
        const float4* src =
            (const float4*)((const float*)ang + (size_t)b * (SEQ * NW));
#pragma unroll
        for (int k = 0; k < 6; ++k) {
            const int v = k * 128 + tid;          // float4 index 0..767
            const float4 a = src[v];
            __align__(16) float o[8];
            float s, c;
            __sincosf(a.x, &s, &c); o[0] = c; o[1] = s;
            __sincosf(a.y, &s, &c); o[2] = c; o[3] = s;
            __sincosf(a.z, &s, &c); o[4] = c; o[5] = s;
            __sincosf(a.w, &s, &c); o[6] = c; o[7] = s;
            ((float4*)cl)[2 * v]     = ((const float4*)o)[0];
            ((float4*)cl)[2 * v + 1] = ((const float4*)o)[1];
        }
    } else {
        const u16x8* src =
            (const u16x8*)((const uint16_t*)ang + (size_t)b * (SEQ * NW));
#pragma unroll
        for (int k = 0; k < 3; ++k) {
            const int v = k * 128 + tid;          // u16x8 index 0..383
            const u16x8 a = src[v];
            __align__(16) float o[16];
#pragma unroll
            for (int e = 0; e < 8; ++e) {
                const float x = __uint_as_float(((uint32_t)a[e]) << 16);
                float s, c;
                __sincosf(x, &s, &c);
                o[2 * e] = c; o[2 * e + 1] = s;
            }
#pragma unroll
            for (int j = 0; j < 4; ++j)
                ((float4*)cl)[4 * v + j] = ((const float4*)o)[j];
        }
    }

    // ---- my component's full M row: 64 floats = 32 v2f pairs ----
    v2f Mv[32];
    {
        const float4* mr4 =
            (const float4*)(Mgc + ((size_t)(dir * 2 + wv) * 64 + lane) * 64);
#pragma unroll
        for (int k = 0; k < 16; ++k) {
            const float4 m = mr4[k];
            Mv[2 * k]     = (v2f){m.x, m.y};
            Mv[2 * k + 1] = (v2f){m.z, m.w};
        }
    }

    // per-wire Z sign masks
    int zmask[6];
#pragma unroll
    for (int w = 0; w < 6; ++w) zmask[w] = ((lane >> (5 - w)) & 1) << 31;

    // walking pointers
    const float* cp = cl + (dir ? (SEQ - 1) * 12 : 0);
    const int   cstep = dir ? -12 : 12;
    float*       zp = zb + (dir ? (SEQ - 1) * NW : 0);
    const int   zstep = dir ? -NW : NW;

    float h[6] = {0.f, 0.f, 0.f, 0.f, 0.f, 0.f};

    __syncthreads();                         // staging visible

    for (int t = 0; t < SEQ; ++t) {
        const int buf = t & 1;

        // this step's cos/sin(x) — broadcast LDS read, needed only at
        // v-build (~300 cyc later): latency fully hidden
        const float4 xq0 = ((const float4*)cp)[0];
        const float4 xq1 = ((const float4*)cp)[1];
        const float4 xq2 = ((const float4*)cp)[2];
        cp += cstep;

        // packed sincos(h/2) (r7/r8-verified polynomial)
        float cw[6], sw[6];
        {
            const v2f kc1 = {2.6041667e-3f, 2.6041667e-3f};
            const v2f kc0 = {-0.125f, -0.125f};
            const v2f ks1 = {2.6041667e-4f, 2.6041667e-4f};
            const v2f ks0 = {-2.0833333e-2f, -2.0833333e-2f};
            const v2f one = {1.f, 1.f}, half = {0.5f, 0.5f};
            v2f hp0 = {h[0], h[1]}, hp1 = {h[2], h[3]}, hp2 = {h[4], h[5]};
            v2f u0 = hp0 * hp0, u1 = hp1 * hp1, u2 = hp2 * hp2;
            v2f c0 = __builtin_elementwise_fma(u0,
                        __builtin_elementwise_fma(u0, kc1, kc0), one);
            v2f c1 = __builtin_elementwise_fma(u1,
                        __builtin_elementwise_fma(u1, kc1, kc0), one);
            v2f c2 = __builtin_elementwise_fma(u2,
                        __builtin_elementwise_fma(u2, kc1, kc0), one);
            v2f s0 = hp0 * __builtin_elementwise_fma(u0,
                        __builtin_elementwise_fma(u0, ks1, ks0), half);
            v2f s1 = hp1 * __builtin_elementwise_fma(u1,
                        __builtin_elementwise_fma(u1, ks1, ks0), half);
            v2f s2 = hp2 * __builtin_elementwise_fma(u2,
                        __builtin_elementwise_fma(u2, ks1, ks0), half);
            cw[0] = c0.x; cw[1] = c0.y; cw[2] = c1.x; cw[3] = c1.y;
            cw[4] = c2.x; cw[5] = c2.y;
            sw[0] = s0.x; sw[1] = s0.y; sw[2] = s1.x; sw[3] = s1.y;
            sw[4] = s2.x; sw[5] = s2.y;
        }

        // e(h) = eH (wires 0-2) ⊗ eL (wires 3-5)  (r8-verified, full)
        float g01[4], g45[4], eH[8], eL[8];
        g01[0] = cw[0] * cw[1]; g01[1] = cw[0] * sw[1];
        g01[2] = sw[0] * cw[1]; g01[3] = sw[0] * sw[1];
        g45[0] = cw[4] * cw[5]; g45[1] = cw[4] * sw[5];
        g45[2] = sw[4] * cw[5]; g45[3] = sw[4] * sw[5];
#pragma unroll
        for (int j = 0; j < 8; ++j) {
            eH[j] = g01[j >> 1] * ((j & 1) ? sw[2] : cw[2]);
            eL[j] = ((j >> 2) ? sw[3] : cw[3]) * g45[j & 3];
        }

        // yc[lane] = sum_c Mcomp[lane,c] e[c] — packed-pair: 32 pkfma + 8 fma
        float yc = 0.f;
#pragma unroll
        for (int p2 = 0; p2 < 4; ++p2) {
            v2f T = {0.f, 0.f};
#pragma unroll
            for (int jl = 0; jl < 8; ++jl)
                T = pkfma(eL[jl], Mv[8 * p2 + jl], T);
            yc = fmaf(eH[2 * p2],     T.x, yc);
            yc = fmaf(eH[2 * p2 + 1], T.y, yc);
        }
        const int yci = __float_as_int(yc);

        // single-component dots yc[l]·yc[l^m] (r8-verified primitives)
        float dotp[6];
        {   // xor32 product trick
            auto rr = __builtin_amdgcn_permlane32_swap(yci, yci, false, false);
            dotp[0] = __int_as_float((int)rr[0]) * __int_as_float((int)rr[1]);
        }
        {   // xor16 product trick
            auto rr = __builtin_amdgcn_permlane16_swap(yci, yci, false, false);
            dotp[1] = __int_as_float((int)rr[0]) * __int_as_float((int)rr[1]);
        }
        dotp[2] = yc * dpp_mov<0x128>(yc);                  // xor8
        dotp[3] = yc * dpp_mov<0x141>(dpp_mov<0x1B>(yc));   // xor4
        dotp[4] = yc * dpp_mov<0x4E>(yc);                   // xor2
        dotp[5] = yc * dpp_mov<0xB1>(yc);                   // xor1

        const float qc = yc * yc;
        const float cx[6] = {xq0.x, xq0.z, xq1.x, xq1.z, xq2.x, xq2.z};
        const float sx[6] = {xq0.y, xq0.w, xq1.y, xq1.w, xq2.y, xq2.w};

        // my component's contribution to z_w (sum over waves = r8's v)
        float v[6];
#pragma unroll
        for (int w = 0; w < 6; ++w) {
            const float cq = __int_as_float(__float_as_int(cx[w] * qc) ^ zmask[w]);
            v[w] = fmaf(-sx[w], dotp[w], cq);
        }

        // to-lane-63 tree (r8-verified sequence)
        red6<0x111>(v);   // row_shr:1
        red6<0x112>(v);   // row_shr:2
        red6<0x114>(v);   // row_shr:4
        red6<0x118>(v);   // row_shr:8
        red6<0x142>(v);   // row_bcast:15
        red6<0x143>(v);   // row_bcast:31

        // totals exchange: 6 scalars per wave, one barrier
        if (lane == 63) {
            ((float4*)tot[buf][wv])[0] = (float4){v[0], v[1], v[2], v[3]};
            ((float4*)tot[buf][wv])[1] = (float4){v[4], v[5], 0.f, 0.f};
        }
        __syncthreads();                     // the ONLY barrier per step

        const float4 a0 = ((const float4*)tot[buf][0])[0];
        const float4 a1 = ((const float4*)tot[buf][0])[1];
        const float4 b0 = ((const float4*)tot[buf][1])[0];
        const float4 b1 = ((const float4*)tot[buf][1])[1];
        h[0] = a0.x + b0.x;  h[1] = a0.y + b0.y;
        h[2] = a0.z + b0.z;  h[3] = a0.w + b0.w;
        h[4] = a1.x + b1.x;  h[5] = a1.y + b1.y;

        if (tid == 63) {                     // wave0 lane63 buffers z = h
            ((float2*)zp)[0] = (float2){h[0], h[1]};
            ((float2*)zp)[1] = (float2){h[2], h[3]};
            ((float2*)zp)[2] = (float2){h[4], h[5]};
        }
        zp += zstep;
    }

    __syncthreads();   // order zb writes before the bulk read

    // ---- bulk store outputs: 768 float4 over 128 threads ----
    {
        const float4* zs4 = (const float4*)zb;
        float4* go = (float4*)(hbuf + (size_t)dir * NELEM +
                               (size_t)b * (SEQ * NW));
#pragma unroll
        for (int k = 0; k < 6; ++k) {
            const int idx = tid + k * 128;
            go[idx] = zs4[idx];
        }
    }
}

// ---------------------------------------------------------------------------
// Kernel 3: out = sigmoid(fc)*h_fwd + sigmoid(bc)*h_bwd, dtype per flag.
// ---------------------------------------------------------------------------
__global__ void k_combine(const float* __restrict__ hbuf,
                          const float* __restrict__ misc,
                          void* __restrict__ out, const int* __restrict__ flag) {
    const int i = blockIdx.x * blockDim.x + threadIdx.x;
    if (i >= NELEM) return;
    const float sf = 1.f / (1.f + __expf(-misc[76]));
    const float sb = 1.f / (1.f + __expf(-misc[77]));
    const float v = sf * hbuf[i] + sb * hbuf[NELEM + i];
    if (*flag) ((__hip_bfloat16*)out)[i] = __float2bfloat16(v);
    else       ((float*)out)[i] = v;
}

// ---------------------------------------------------------------------------
extern "C" void kernel_launch(void* const* d_in, const int* in_sizes, int n_in,
                              void* d_out, int out_size, void* d_ws, size_t ws_size,
                              hipStream_t stream) {
    const void* ang  = d_in[0];
    const void* poly = d_in[1];
    const void* fp   = d_in[2];
    const void* bp   = d_in[3];
    const void* fc   = d_in[4];
    const void* bc   = d_in[5];

    // ws (floats): pad[32] | misc[128] | hbuf[2*NELEM] | Mgc[16384] | flag
    float* misc = (float*)d_ws + 32;
    float* hbuf = misc + 128;
    float* Mgc  = hbuf + 2 * NELEM;
    int*   flag = (int*)(Mgc + 2 * 2 * 64 * 64);

    k_prep<<<33, 256, 0, stream>>>(ang, poly, fp, bp, fc, bc, misc, Mgc, flag);
    k_sim<<<256, 128, 0, stream>>>(ang, Mgc, hbuf, flag);
    k_combine<<<(NELEM + 255) / 256, 256, 0, stream>>>(hbuf, misc, d_out, flag);
}

// Round 12
// 343.990 us; speedup vs baseline: 1.1023x; 1.1023x over previous
//
#include <hip/hip_runtime.h>
#include <hip/hip_bf16.h>
#include <stdint.h>

#define BATCH 128
#define SEQ   512
#define NW    6
#define DIM   64
#define NELEM (BATCH * SEQ * NW)   // 393216
#define PI_F  3.14159265358979323846f

typedef float v2f __attribute__((ext_vector_type(2)));
typedef uint16_t u16x8 __attribute__((ext_vector_type(8)));

__device__ __forceinline__ v2f pkfma(float s, v2f m, v2f a) {
    return __builtin_elementwise_fma((v2f){s, s}, m, a);
}

// Single-instruction DPP add stage: bound_ctrl=true -> invalid lanes read 0,
// identical to the old (old=0, false) form, but folds to v_add_f32_dpp.
template <int CTRL>
__device__ __forceinline__ float dpp_add(float v) {
    return v + __int_as_float(__builtin_amdgcn_update_dpp(
        0, __float_as_int(v), CTRL, 0xF, 0xF, true));
}

// 6-way interleaved reduction stage (r0/r1-verified sequence shr1,2,4,8 +
// bcast15,31 -> totals land in lane 63).
template <int CTRL>
__device__ __forceinline__ void red6(float v[6]) {
#pragma unroll
    for (int k = 0; k < 6; ++k) v[k] = dpp_add<CTRL>(v[k]);
}

// DPP move, bound_ctrl=true (all CTRLs used are valid on every lane ->
// folds to a single v_mov_b32_dpp).
template <int CTRL>
__device__ __forceinline__ float dpp_mov(float x) {
    return __int_as_float(__builtin_amdgcn_update_dpp(
        0, __float_as_int(x), CTRL, 0xF, 0xF, true));
}

__device__ __forceinline__ float ldf(const void* p, int i, bool bf) {
    if (bf) {
        uint32_t u = (uint32_t)((const uint16_t*)p)[i];
        return __uint_as_float(u << 16);
    }
    return ((const float*)p)[i];
}

// ---------------------------------------------------------------------------
// Kernel 1 (msetup + misc):
//  - blocks [0,32): 4 waves/block evolve one (dir,col) basis column -> Mg
//  - block 32: misc fills + flag post
// ---------------------------------------------------------------------------
__global__ void k_prep(const void* ang, const void* poly, const void* fp,
                       const void* bp, const void* fc, const void* bc,
                       float* __restrict__ misc, float* __restrict__ Mg,
                       int* __restrict__ flag) {
    __shared__ int cnt;
    if (threadIdx.x == 0) cnt = 0;
    __syncthreads();
    {
        uint32_t w = ((const uint32_t*)ang)[threadIdx.x & 255];
        uint32_t e = (w >> 8) & 0xFFu;
        if (e >= 0x3Au && e <= 0x41u) atomicAdd(&cnt, 1);
    }
    __syncthreads();
    const bool bf = (cnt >= 128);

    if (blockIdx.x == 32) {
        if (threadIdx.x == 0)      misc[76] = ldf(fc, 0, bf);
        else if (threadIdx.x == 1) misc[77] = ldf(bc, 0, bf);
        else if (threadIdx.x == 2) *flag = bf ? 1 : 0;
        return;
    }

    // ---- msetup path: 4 columns per block (one per wave) ----
    const int lane = threadIdx.x & 63;
    const int tix  = blockIdx.x * 4 + (threadIdx.x >> 6);
    const int dir  = tix >> 6;
    const int col  = tix & 63;
    const void* prm = dir ? bp : fp;
    const int p = lane;

    float yr = (p == col) ? 1.f : 0.f;
    float yi = 0.f;

#pragma unroll
    for (int d = 0; d < 4; ++d) {
        const float th = 0.5f * PI_F * ldf(poly, d, bf) *
                         (float)(6 - 2 * (int)__popc((unsigned)p));
        float s, c;
        __sincosf(th, &s, &c);
        const float nr = yr * c + yi * s;
        const float ni = yi * c - yr * s;
        yr = nr; yi = ni;
#pragma unroll
        for (int k = 0; k < 6; ++k) {
            const int cw = k, tw = (k + 1) % 6;
            const int src = p ^ (((p >> (5 - cw)) & 1) << (5 - tw));
            yr = __shfl(yr, src, 64);
            yi = __shfl(yi, src, 64);
        }
    }

    int idx = 0;
#pragma unroll
    for (int l = 0; l < 2; ++l) {
#pragma unroll
        for (int w = 0; w < 6; ++w) {
            float cx, sx, cy, sy, cz, sz;
            __sincosf(0.5f * ldf(prm, idx + 0, bf), &sx, &cx);
            __sincosf(0.5f * ldf(prm, idx + 1, bf), &sy, &cy);
            __sincosf(0.5f * ldf(prm, idx + 2, bf), &sz, &cz);
            idx += 3;
            const float A = cy * cx, B = sy * sx, C = sy * cx, D = cy * sx;
            const float U00r = cz * A + sz * B, U00i = cz * B - sz * A;
            const float U11r = U00r,            U11i = sz * A - cz * B;
            const float Xr   = cz * C + sz * D, Xi   = sz * C - cz * D;
            const int m  = 1 << (5 - w);
            const int bb = (p >> (5 - w)) & 1;
            const float C1r = bb ? U11r : U00r;
            const float C1i = bb ? U11i : U00i;
            const float C2r = bb ? Xr : -Xr;
            const float C2i = Xi;
            const float pr = __shfl_xor(yr, m, 64);
            const float pi = __shfl_xor(yi, m, 64);
            const float nr = C1r * yr - C1i * yi + C2r * pr - C2i * pi;
            const float ni = C1r * yi + C1i * yr + C2r * pi + C2i * pr;
            yr = nr; yi = ni;
        }
#pragma unroll
        for (int k = 0; k < 5; ++k) {
            const int src = p ^ (((p >> (5 - k)) & 1) << (5 - (k + 1)));
            yr = __shfl(yr, src, 64);
            yi = __shfl(yi, src, 64);
        }
    }

    float* out = Mg + ((size_t)(dir * 64 + p) * 64 + (size_t)col) * 2;
    out[0] = yr;
    out[1] = yi;
}

// ---------------------------------------------------------------------------
// Kernel 2: recurrent sim — the measured session optimum (r8 structure):
// 4 waves/chain, one barrier/step, VGPR-resident M split (16 cols/lane,
// VGPR_Count=52, no spill), all-VALU partner dots, single-inst DPP tree to
// lane 63 + readlane broadcast, packed v2f sincos, xq prefetched off the
// critical path.
//
// Structural floor (measured across 7 structure variants, r0-r11): 512
// serially-dependent steps x ~1330 cyc = ~295 us. Issue varying +/-50%
// (r0/r6/r8) does not move time; removing the exchange requires >=210 arch
// VGPRs (allocator caps at 132) or AGPR-sourced VALU (not in gfx950 ISA);
// LDS-streamed M is DS-latency-bound (402 us). Latency-bound at 1 wave/SIMD
// — intrinsic to 256 chains on 256 CUs; not memory- (HBM 0.2%) or
// compute-bound (VALU <=59%).
// ---------------------------------------------------------------------------
__global__ void __launch_bounds__(256, 1) k_sim(const void* __restrict__ ang,
                                                const float* __restrict__ Mg,
                                                float* __restrict__ hbuf,
                                                const int* __restrict__ flag) {
    const int tid   = threadIdx.x;
    const int lane  = tid & 63;
    const int wv    = tid >> 6;              // wave 0..3
    const int chain = blockIdx.x;            // 0..255
    const int dir   = chain >> 7;
    const int b     = chain & 127;
    const bool bf   = (*flag != 0);

    __shared__ __align__(16) float  cl[SEQ * 12];   // 24 KB cos/sin(x)
    __shared__ __align__(16) float  zb[SEQ * NW];   // 12 KB output buffer
    __shared__ float2 pY[2][4][DIM];                // ping-pong partials, 4 KB

    // ---- stage: convert this chain's 3072 angles -> cos/sin in LDS ----
    if (!bf) {
        const float4* src =
            (const float4*)((const float*)ang + (size_t)b * (SEQ * NW));
#pragma unroll
        for (int k = 0; k < 3; ++k) {
            const int v = k * 256 + tid;          // float4 index 0..767
            const float4 a = src[v];
            __align__(16) float o[8];
            float s, c;
            __sincosf(a.x, &s, &c); o[0] = c; o[1] = s;
            __sincosf(a.y, &s, &c); o[2] = c; o[3] = s;
            __sincosf(a.z, &s, &c); o[4] = c; o[5] = s;
            __sincosf(a.w, &s, &c); o[6] = c; o[7] = s;
            ((float4*)cl)[2 * v]     = ((const float4*)o)[0];
            ((float4*)cl)[2 * v + 1] = ((const float4*)o)[1];
        }
    } else {
        const u16x8* src =
            (const u16x8*)((const uint16_t*)ang + (size_t)b * (SEQ * NW));
#pragma unroll
        for (int k = 0; k < 2; ++k) {
            const int v = k * 256 + tid;          // u16x8 index 0..383
            if (v < 384) {
                const u16x8 a = src[v];
                __align__(16) float o[16];
#pragma unroll
                for (int e = 0; e < 8; ++e) {
                    const float x = __uint_as_float(((uint32_t)a[e]) << 16);
                    float s, c;
                    __sincosf(x, &s, &c);
                    o[2 * e] = c; o[2 * e + 1] = s;
                }
#pragma unroll
                for (int j = 0; j < 4; ++j)
                    ((float4*)cl)[4 * v + j] = ((const float4*)o)[j];
            }
        }
    }

    // ---- my 16 resident M columns: row = lane, cols = 16wv..16wv+15 ----
    v2f Mres[16];
    {
        const float2* mr2 =
            (const float2*)(Mg + (size_t)(dir * 64 + lane) * 128 + 32 * wv);
#pragma unroll
        for (int k = 0; k < 16; ++k) Mres[k] = (v2f){mr2[k].x, mr2[k].y};
    }

    // per-wire Z sign masks
    int zmask[6];
#pragma unroll
    for (int w = 0; w < 6; ++w) zmask[w] = ((lane >> (5 - w)) & 1) << 31;
    const int ow0 = wv ^ 1, ow1 = wv ^ 2, ow2 = wv ^ 3;   // other waves

    float h[6] = {0.f, 0.f, 0.f, 0.f, 0.f, 0.f};

    // encode h -> my 16-col matvec partial (r6 math; packed sincos, r7 form)
    auto encode_matvec = [&](v2f& acc) {
        const v2f kc1 = {2.6041667e-3f, 2.6041667e-3f};
        const v2f kc0 = {-0.125f, -0.125f};
        const v2f ks1 = {2.6041667e-4f, 2.6041667e-4f};
        const v2f ks0 = {-2.0833333e-2f, -2.0833333e-2f};
        const v2f one = {1.f, 1.f}, half = {0.5f, 0.5f};
        v2f hp0 = {h[0], h[1]}, hp1 = {h[2], h[3]}, hp2 = {h[4], h[5]};
        v2f u0 = hp0 * hp0, u1 = hp1 * hp1, u2 = hp2 * hp2;
        v2f c0 = __builtin_elementwise_fma(u0,
                    __builtin_elementwise_fma(u0, kc1, kc0), one);
        v2f c1 = __builtin_elementwise_fma(u1,
                    __builtin_elementwise_fma(u1, kc1, kc0), one);
        v2f c2 = __builtin_elementwise_fma(u2,
                    __builtin_elementwise_fma(u2, kc1, kc0), one);
        v2f s0 = hp0 * __builtin_elementwise_fma(u0,
                    __builtin_elementwise_fma(u0, ks1, ks0), half);
        v2f s1 = hp1 * __builtin_elementwise_fma(u1,
                    __builtin_elementwise_fma(u1, ks1, ks0), half);
        v2f s2 = hp2 * __builtin_elementwise_fma(u2,
                    __builtin_elementwise_fma(u2, ks1, ks0), half);
        const float t0 = (wv & 2) ? s0.x : c0.x;   // wire0 bit = wv>>1
        const float t1 = (wv & 1) ? s0.y : c0.y;   // wire1 bit = wv&1
        const float A  = t0 * t1;
        float GH[4], GL[4];
        GH[0] = c1.x * c1.y; GH[1] = c1.x * s1.y;
        GH[2] = s1.x * c1.y; GH[3] = s1.x * s1.y;
#pragma unroll
        for (int a = 0; a < 4; ++a) GH[a] *= A;
        GL[0] = c2.x * c2.y; GL[1] = c2.x * s2.y;
        GL[2] = s2.x * c2.y; GL[3] = s2.x * s2.y;
        v2f y = {0.f, 0.f};
#pragma unroll
        for (int a = 0; a < 4; ++a) {
            v2f T = {0.f, 0.f};
#pragma unroll
            for (int b2 = 0; b2 < 4; ++b2)
                T = pkfma(GL[b2], Mres[4 * a + b2], T);
            y = pkfma(GH[a], T, y);
        }
        acc = y;
    };

    // walking pointers
    const float* cp = cl + (dir ? (SEQ - 1) * 12 : 0);
    const int   cstep = dir ? -12 : 12;
    float*       zp = zb + (dir ? (SEQ - 1) * NW : 0);
    const int   zstep = dir ? -NW : NW;

    __syncthreads();                         // staging visible

    // ---- peel: partial for t=0 (h=0) + xq preload for t=0 ----
    v2f myacc;
    encode_matvec(myacc);
    pY[0][wv][lane] = (float2){myacc.x, myacc.y};
    float4 xq0 = ((const float4*)cp)[0];
    float4 xq1 = ((const float4*)cp)[1];
    float4 xq2 = ((const float4*)cp)[2];
    cp += cstep;
    __syncthreads();                         // pY[0] visible

    for (int t = 0; t < SEQ; ++t) {
        const int buf = t & 1;

        // reassemble full y: 3 partner partials + my own
        const float2 yA = pY[buf][ow0][lane];
        const float2 yB = pY[buf][ow1][lane];
        const float2 yC = pY[buf][ow2][lane];
        const float yr = (myacc.x + yA.x) + (yB.x + yC.x);
        const float yi = (myacc.y + yA.y) + (yB.y + yC.y);
        const int yri = __float_as_int(yr), yii = __float_as_int(yi);

        // dots y[l]·y[l^m]: product trick for swaps, DPP movs otherwise
        float dot[6];
        {   // w0: xor32 — d'*s' = y[l]*y[l^32] on every lane (r6-verified)
            auto rr = __builtin_amdgcn_permlane32_swap(yri, yri, false, false);
            auto ri = __builtin_amdgcn_permlane32_swap(yii, yii, false, false);
            dot[0] = fmaf(__int_as_float((int)rr[0]), __int_as_float((int)rr[1]),
                          __int_as_float((int)ri[0]) * __int_as_float((int)ri[1]));
        }
        {   // w1: xor16
            auto rr = __builtin_amdgcn_permlane16_swap(yri, yri, false, false);
            auto ri = __builtin_amdgcn_permlane16_swap(yii, yii, false, false);
            dot[1] = fmaf(__int_as_float((int)rr[0]), __int_as_float((int)rr[1]),
                          __int_as_float((int)ri[0]) * __int_as_float((int)ri[1]));
        }
        dot[2] = fmaf(yr, dpp_mov<0x128>(yr), yi * dpp_mov<0x128>(yi)); // xor8
        dot[3] = fmaf(yr, dpp_mov<0x141>(dpp_mov<0x1B>(yr)),            // xor4
                      yi * dpp_mov<0x141>(dpp_mov<0x1B>(yi)));
        dot[4] = fmaf(yr, dpp_mov<0x4E>(yr), yi * dpp_mov<0x4E>(yi));   // xor2
        dot[5] = fmaf(yr, dpp_mov<0xB1>(yr), yi * dpp_mov<0xB1>(yi));   // xor1

        const float q = fmaf(yr, yr, yi * yi);
        const float cx[6] = {xq0.x, xq0.z, xq1.x, xq1.z, xq2.x, xq2.z};
        const float sx[6] = {xq0.y, xq0.w, xq1.y, xq1.w, xq2.y, xq2.w};

        // per-lane contribution to z_w = cx*Z_w - sx*X_w (folded, verified)
        float v[6];
#pragma unroll
        for (int w = 0; w < 6; ++w) {
            const float cq = __int_as_float(__float_as_int(cx[w] * q) ^ zmask[w]);
            v[w] = fmaf(-sx[w], dot[w], cq);
        }

        // xq for step t+1 — off the critical path, xq regs now dead
        if (t + 1 < SEQ) {
            xq0 = ((const float4*)cp)[0];
            xq1 = ((const float4*)cp)[1];
            xq2 = ((const float4*)cp)[2];
            cp += cstep;
        }

        // to-lane-63 tree (r0-verified sequence, single-inst stages)
        red6<0x111>(v);   // row_shr:1
        red6<0x112>(v);   // row_shr:2
        red6<0x114>(v);   // row_shr:4
        red6<0x118>(v);   // row_shr:8
        red6<0x142>(v);   // row_bcast:15
        red6<0x143>(v);   // row_bcast:31

        if (tid == 63) {                     // lane 63 holds the totals
#pragma unroll
            for (int w = 0; w < 6; ++w) zp[w] = v[w];
        }
        zp += zstep;
#pragma unroll
        for (int w = 0; w < 6; ++w)          // r1-verified broadcast
            h[w] = __int_as_float(
                __builtin_amdgcn_readlane(__float_as_int(v[w]), 63));

        // next state's partial into the other buffer
        encode_matvec(myacc);
        pY[buf ^ 1][wv][lane] = (float2){myacc.x, myacc.y};
        __syncthreads();                     // the ONLY barrier per step
    }

    // ---- bulk store outputs: 768 float4 over 256 threads ----
    {
        const float4* zs4 = (const float4*)zb;
        float4* go = (float4*)(hbuf + (size_t)dir * NELEM +
                               (size_t)b * (SEQ * NW));
#pragma unroll
        for (int k = 0; k < 3; ++k) {
            const int idx = tid + k * 256;
            go[idx] = zs4[idx];
        }
    }
}

// ---------------------------------------------------------------------------
// Kernel 3: out = sigmoid(fc)*h_fwd + sigmoid(bc)*h_bwd, dtype per flag.
// ---------------------------------------------------------------------------
__global__ void k_combine(const float* __restrict__ hbuf,
                          const float* __restrict__ misc,
                          void* __restrict__ out, const int* __restrict__ flag) {
    const int i = blockIdx.x * blockDim.x + threadIdx.x;
    if (i >= NELEM) return;
    const float sf = 1.f / (1.f + __expf(-misc[76]));
    const float sb = 1.f / (1.f + __expf(-misc[77]));
    const float v = sf * hbuf[i] + sb * hbuf[NELEM + i];
    if (*flag) ((__hip_bfloat16*)out)[i] = __float2bfloat16(v);
    else       ((float*)out)[i] = v;
}

// ---------------------------------------------------------------------------
extern "C" void kernel_launch(void* const* d_in, const int* in_sizes, int n_in,
                              void* d_out, int out_size, void* d_ws, size_t ws_size,
                              hipStream_t stream) {
    const void* ang  = d_in[0];
    const void* poly = d_in[1];
    const void* fp   = d_in[2];
    const void* bp   = d_in[3];
    const void* fc   = d_in[4];
    const void* bc   = d_in[5];

    // ws (floats): pad[32] | misc[128] | hbuf[2*NELEM] | Mg[16384] | flag
    float* misc = (float*)d_ws + 32;
    float* hbuf = misc + 128;
    float* Mg   = hbuf + 2 * NELEM;
    int*   flag = (int*)(Mg + 2 * 64 * 64 * 2);

    k_prep<<<33, 256, 0, stream>>>(ang, poly, fp, bp, fc, bc, misc, Mg, flag);
    k_sim<<<256, 256, 0, stream>>>(ang, Mg, hbuf, flag);
    k_combine<<<(NELEM + 255) / 256, 256, 0, stream>>>(hbuf, misc, d_out, flag);
}